// Round 2
// baseline (1005.619 us; speedup 1.0000x reference)
//
#include <hip/hip_runtime.h>
#include <hip/hip_bf16.h>

using bf16 = __hip_bfloat16;

__device__ __forceinline__ float b2f(bf16 v) { return __bfloat162float(v); }
__device__ __forceinline__ bf16 f2b(float f) { return __float2bfloat16(f); }

#define B 8
#define CIN 256
#define HW 4096
#define QKV_CH 768
#define PROJ_IN 512
#define PROJ_OUT 256

// K1: qkv = w_qkv(768x256) @ x(b,256,4096) -> bf16
// block 256 = 8 o-threads x 32 p-threads; tile 32 o x 128 p; micro 4o x 4p
__global__ __launch_bounds__(256) void k_qkv(const float* __restrict__ x,
                                             const float* __restrict__ w,
                                             bf16* __restrict__ qkv) {
    int tid = threadIdx.x;
    int to = tid >> 5, tp = tid & 31;
    int pg = blockIdx.x, og = blockIdx.y, b = blockIdx.z;

    __shared__ float sw[256 * 36];  // sw[c*36 + o_local], 36 KB, 16B-aligned rows

    // stage 32x256 weight tile (coalesced read, transposed write)
    for (int i = tid; i < 32 * 256; i += 256) {
        int o = i >> 8, c = i & 255;
        sw[c * 36 + o] = w[(size_t)(og * 32 + o) * 256 + c];
    }
    __syncthreads();

    float acc[4][4];
#pragma unroll
    for (int j = 0; j < 4; ++j)
#pragma unroll
        for (int i = 0; i < 4; ++i) acc[j][i] = 0.f;

    const float* xp = x + (size_t)b * CIN * HW + pg * 128 + tp * 4;
#pragma unroll 4
    for (int c = 0; c < 256; ++c) {
        float4 xv = *(const float4*)(xp + (size_t)c * HW);
        float4 wv = *(const float4*)(&sw[c * 36 + to * 4]);
        acc[0][0] += wv.x * xv.x; acc[0][1] += wv.x * xv.y; acc[0][2] += wv.x * xv.z; acc[0][3] += wv.x * xv.w;
        acc[1][0] += wv.y * xv.x; acc[1][1] += wv.y * xv.y; acc[1][2] += wv.y * xv.z; acc[1][3] += wv.y * xv.w;
        acc[2][0] += wv.z * xv.x; acc[2][1] += wv.z * xv.y; acc[2][2] += wv.z * xv.z; acc[2][3] += wv.z * xv.w;
        acc[3][0] += wv.w * xv.x; acc[3][1] += wv.w * xv.y; acc[3][2] += wv.w * xv.z; acc[3][3] += wv.w * xv.w;
    }

#pragma unroll
    for (int j = 0; j < 4; ++j) {
        int o = og * 32 + to * 4 + j;
        bf16* base = qkv + ((size_t)b * QKV_CH + o) * HW + pg * 128 + tp * 4;
#pragma unroll
        for (int i = 0; i < 4; ++i) base[i] = f2b(acc[j][i]);
    }
}

// K2: depthwise 5x5, pad 2 (cross-correlation), per channel
__global__ void k_dw(const bf16* __restrict__ qkv, const float* __restrict__ wdw,
                     bf16* __restrict__ dw) {
    int p = blockIdx.x * 256 + threadIdx.x;
    int c = blockIdx.y;
    int b = blockIdx.z;
    int y = p >> 6, xc = p & 63;
    const bf16* src = qkv + ((size_t)b * QKV_CH + c) * HW;
    const float* wp = wdw + (size_t)c * 25;
    float acc = 0.f;
#pragma unroll
    for (int ky = 0; ky < 5; ++ky) {
        int yy = y + ky - 2;
        if (yy < 0 || yy > 63) continue;
#pragma unroll
        for (int kx = 0; kx < 5; ++kx) {
            int xx = xc + kx - 2;
            if (xx < 0 || xx > 63) continue;
            acc += wp[ky * 5 + kx] * b2f(src[yy * 64 + xx]);
        }
    }
    dw[((size_t)b * QKV_CH + c) * HW + p] = f2b(acc);
}

// K3: group pointwise 8->8 per group g, IN-PLACE on dw buffer
__global__ void k_agg(bf16* __restrict__ dw, const float* __restrict__ wpw) {
    int p = blockIdx.x * 256 + threadIdx.x;
    int g = blockIdx.y;
    int b = blockIdx.z;
    bf16* base = dw + ((size_t)b * QKV_CH + g * 8) * HW + p;
    float in[8];
#pragma unroll
    for (int i = 0; i < 8; ++i) in[i] = b2f(base[(size_t)i * HW]);
    const float* wp = wpw + (size_t)g * 64;
    float out[8];
#pragma unroll
    for (int o = 0; o < 8; ++o) {
        float acc = 0.f;
#pragma unroll
        for (int i = 0; i < 8; ++i) acc += wp[o * 8 + i] * in[i];
        out[o] = acc;
    }
#pragma unroll
    for (int o = 0; o < 8; ++o) base[(size_t)o * HW] = f2b(out[o]);
}

// K4: linear attention per (b,h): kv = sum_p relu(k) (x) [v,1]; out = q.kv / (q.kv_last + eps)
__global__ void k_attn(const bf16* __restrict__ qkv, const bf16* __restrict__ agg,
                       float* __restrict__ out) {
    int h = blockIdx.x;
    int b = blockIdx.y;
    int tid = threadIdx.x;
    int cbase = 24 * h;
    const bf16* src = (h < 32)
        ? qkv + ((size_t)b * QKV_CH + cbase) * HW
        : agg + ((size_t)b * QKV_CH + (cbase - QKV_CH)) * HW;

    __shared__ float skv[72];
    if (tid < 72) skv[tid] = 0.f;
    __syncthreads();

    float acc[72];
#pragma unroll
    for (int i = 0; i < 72; ++i) acc[i] = 0.f;

    for (int p = tid; p < HW; p += 256) {
        float kk[8], vv[9];
#pragma unroll
        for (int d = 0; d < 8; ++d) {
            float t = b2f(src[(size_t)(8 + d) * HW + p]);
            kk[d] = t > 0.f ? t : 0.f;
        }
#pragma unroll
        for (int e = 0; e < 8; ++e) vv[e] = b2f(src[(size_t)(16 + e) * HW + p]);
        vv[8] = 1.f;
#pragma unroll
        for (int d = 0; d < 8; ++d)
#pragma unroll
            for (int e = 0; e < 9; ++e) acc[d * 9 + e] += kk[d] * vv[e];
    }
#pragma unroll
    for (int i = 0; i < 72; ++i) atomicAdd(&skv[i], acc[i]);
    __syncthreads();

    for (int p = tid; p < HW; p += 256) {
        float q[8];
#pragma unroll
        for (int d = 0; d < 8; ++d) {
            float t = b2f(src[(size_t)d * HW + p]);
            q[d] = t > 0.f ? t : 0.f;
        }
        float num[9];
#pragma unroll
        for (int e = 0; e < 9; ++e) {
            float s = 0.f;
#pragma unroll
            for (int d = 0; d < 8; ++d) s += q[d] * skv[d * 9 + e];
            num[e] = s;
        }
        float inv = 1.f / (num[8] + 1e-15f);
#pragma unroll
        for (int e = 0; e < 8; ++e)
            out[((size_t)b * PROJ_IN + h * 8 + e) * HW + p] = num[e] * inv;
    }
}

// K5: proj conv1x1 (256x512) + BN affine -> d_out fp32
// block 256 = 8 o x 32 p; tile 32 o x 128 p; c staged in 2 chunks of 256
__global__ __launch_bounds__(256) void k_proj(const float* __restrict__ attn,
                                              const float* __restrict__ w,
                                              const float* __restrict__ gamma,
                                              const float* __restrict__ beta,
                                              const float* __restrict__ mean,
                                              const float* __restrict__ var,
                                              float* __restrict__ out) {
    int tid = threadIdx.x;
    int to = tid >> 5, tp = tid & 31;
    int pg = blockIdx.x, og = blockIdx.y, b = blockIdx.z;

    __shared__ float sw[256 * 36];

    float acc[4][4];
#pragma unroll
    for (int j = 0; j < 4; ++j)
#pragma unroll
        for (int i = 0; i < 4; ++i) acc[j][i] = 0.f;

    const float* ap = attn + (size_t)b * PROJ_IN * HW + pg * 128 + tp * 4;

    for (int h = 0; h < 2; ++h) {
        __syncthreads();
        for (int i = tid; i < 32 * 256; i += 256) {
            int o = i >> 8, c = i & 255;
            sw[c * 36 + o] = w[(size_t)(og * 32 + o) * 512 + h * 256 + c];
        }
        __syncthreads();
#pragma unroll 4
        for (int c = 0; c < 256; ++c) {
            float4 xv = *(const float4*)(ap + (size_t)(h * 256 + c) * HW);
            float4 wv = *(const float4*)(&sw[c * 36 + to * 4]);
            acc[0][0] += wv.x * xv.x; acc[0][1] += wv.x * xv.y; acc[0][2] += wv.x * xv.z; acc[0][3] += wv.x * xv.w;
            acc[1][0] += wv.y * xv.x; acc[1][1] += wv.y * xv.y; acc[1][2] += wv.y * xv.z; acc[1][3] += wv.y * xv.w;
            acc[2][0] += wv.z * xv.x; acc[2][1] += wv.z * xv.y; acc[2][2] += wv.z * xv.z; acc[2][3] += wv.z * xv.w;
            acc[3][0] += wv.w * xv.x; acc[3][1] += wv.w * xv.y; acc[3][2] += wv.w * xv.z; acc[3][3] += wv.w * xv.w;
        }
    }

#pragma unroll
    for (int j = 0; j < 4; ++j) {
        int o = og * 32 + to * 4 + j;
        float inv = gamma[o] * rsqrtf(var[o] + 1e-5f);
        float add = beta[o] - mean[o] * inv;
        float4 r;
        r.x = acc[j][0] * inv + add;
        r.y = acc[j][1] * inv + add;
        r.z = acc[j][2] * inv + add;
        r.w = acc[j][3] * inv + add;
        *(float4*)(out + ((size_t)b * PROJ_OUT + o) * HW + pg * 128 + tp * 4) = r;
    }
}

extern "C" void kernel_launch(void* const* d_in, const int* in_sizes, int n_in,
                              void* d_out, int out_size, void* d_ws, size_t ws_size,
                              hipStream_t stream) {
    const float* x      = (const float*)d_in[0];
    const float* w_qkv  = (const float*)d_in[1];
    const float* w_dw   = (const float*)d_in[2];
    const float* w_pw   = (const float*)d_in[3];
    const float* w_proj = (const float*)d_in[4];
    const float* bn_g   = (const float*)d_in[5];
    const float* bn_b   = (const float*)d_in[6];
    const float* bn_m   = (const float*)d_in[7];
    const float* bn_v   = (const float*)d_in[8];
    float* out = (float*)d_out;

    char* ws = (char*)d_ws;
    bf16*  qkv  = (bf16*)(ws);                           // 8*768*4096*2  = 48 MB
    bf16*  dwb  = (bf16*)(ws + (size_t)50331648);        // 48 MB (dw, then agg in-place)
    float* attn = (float*)(ws + (size_t)100663296);      // 8*512*4096*4  = 64 MB

    dim3 blk(256);
    k_qkv <<<dim3(32, 24, B), blk, 0, stream>>>(x, w_qkv, qkv);
    k_dw  <<<dim3(16, QKV_CH, B), blk, 0, stream>>>(qkv, w_dw, dwb);
    k_agg <<<dim3(16, 96, B), blk, 0, stream>>>(dwb, w_pw);
    k_attn<<<dim3(64, B), blk, 0, stream>>>(qkv, dwb, attn);
    k_proj<<<dim3(32, 8, B), blk, 0, stream>>>(attn, w_proj, bn_g, bn_b, bn_m, bn_v, out);
}